// Round 10
// baseline (110.239 us; speedup 1.0000x reference)
//
#include <hip/hip_runtime.h>

#define N_ROWS 4096
#define DIM 1024
#define INV_T (1.0f / 0.07f)
#define FP8_SCALE 16.0f
// acc = (16*c1)·(16*c2) = 256*cos; exp2 argument = acc * INV_T * log2(e) / 256
#define EXP_SCALE (INV_T * 1.44269504088896f / 256.0f)
#define BK 128   // fp8 elements per k-tile (= 128 B rows in LDS) = one MFMA-K
#define NJT 32   // number of j-tiles (= grid.x of gemm)

typedef __attribute__((ext_vector_type(4))) float floatx4;
typedef __attribute__((ext_vector_type(4))) int int4x;
typedef __attribute__((ext_vector_type(8))) int int8x;

// fp32 -> OCP e4m3fn, RNE, FTZ below 2^-6 (|x| <~ 16 here, no overflow path).
__device__ inline unsigned int f2e4m3(float x) {
    unsigned int u = __float_as_uint(x);
    unsigned int s = (u >> 24) & 0x80u;
    int e = (int)((u >> 23) & 0xffu);
    unsigned int m = u & 0x7fffffu;
    if (e < 121) return s;              // FTZ (|x| < 2^-6)
    unsigned int t = m >> 20;
    unsigned int rest = m & 0xFFFFFu;
    t += (rest > 0x80000u) || (rest == 0x80000u && (t & 1u));  // RNE
    int e8 = e - 120;
    if (t == 8u) { t = 0u; e8 += 1; }
    return s | ((unsigned int)e8 << 3) | t;
}

// One WAVE per row (4 rows / 256-thread block). Emits fp8 normalized rows
// (scaled by 16) + exact fp32 diagonal logit. Zeroes S (per-row); block 0
// zeroes ctr[] and out[0]. All plain stores — flushed at kernel boundary,
// visible to the GEMM dispatch.
__global__ __launch_bounds__(256) void k_normalize(
    const float* __restrict__ z1, const float* __restrict__ z2,
    unsigned char* __restrict__ z1f, unsigned char* __restrict__ z2f,
    float* __restrict__ diag, float* __restrict__ S,
    unsigned int* __restrict__ ctr, float* __restrict__ out) {
    const int lane = threadIdx.x & 63, wave = threadIdx.x >> 6;
    const int row = blockIdx.x * 4 + wave;

    if (blockIdx.x == 0) {
        if (threadIdx.x < 32) ctr[threadIdx.x] = 0u;
        else if (threadIdx.x == 32) out[0] = 0.f;
    }

    const float4* A = reinterpret_cast<const float4*>(z1 + (size_t)row * DIM);
    const float4* B = reinterpret_cast<const float4*>(z2 + (size_t)row * DIM);
    float4 a[4], b[4];
    #pragma unroll
    for (int rep = 0; rep < 4; ++rep) {
        a[rep] = A[lane + 64 * rep];
        b[rep] = B[lane + 64 * rep];
    }

    float s11 = 0.f, s22 = 0.f, s12 = 0.f;
    #pragma unroll
    for (int rep = 0; rep < 4; ++rep) {
        s11 += a[rep].x * a[rep].x + a[rep].y * a[rep].y
             + a[rep].z * a[rep].z + a[rep].w * a[rep].w;
        s22 += b[rep].x * b[rep].x + b[rep].y * b[rep].y
             + b[rep].z * b[rep].z + b[rep].w * b[rep].w;
        s12 += a[rep].x * b[rep].x + a[rep].y * b[rep].y
             + a[rep].z * b[rep].z + a[rep].w * b[rep].w;
    }
    #pragma unroll
    for (int m = 32; m >= 1; m >>= 1) {
        s11 += __shfl_xor(s11, m, 64);
        s22 += __shfl_xor(s22, m, 64);
        s12 += __shfl_xor(s12, m, 64);
    }

    const float n1 = fmaxf(sqrtf(s11), 1e-12f);
    const float n2 = fmaxf(sqrtf(s22), 1e-12f);
    if (lane == 0) {
        diag[row] = s12 / (n1 * n2) * INV_T;
        S[row] = 0.f;
    }
    const float i1 = FP8_SCALE / n1, i2 = FP8_SCALE / n2;

    unsigned int* O1 = reinterpret_cast<unsigned int*>(z1f + (size_t)row * DIM);
    unsigned int* O2 = reinterpret_cast<unsigned int*>(z2f + (size_t)row * DIM);
    #pragma unroll
    for (int rep = 0; rep < 4; ++rep) {
        unsigned int pa = f2e4m3(a[rep].x * i1) | (f2e4m3(a[rep].y * i1) << 8)
                        | (f2e4m3(a[rep].z * i1) << 16) | (f2e4m3(a[rep].w * i1) << 24);
        unsigned int pb = f2e4m3(b[rep].x * i2) | (f2e4m3(b[rep].y * i2) << 8)
                        | (f2e4m3(b[rep].z * i2) << 16) | (f2e4m3(b[rep].w * i2) << 24);
        O1[lane + 64 * rep] = pa;
        O2[lane + 64 * rep] = pb;
    }
}

// MX-scaled fp8 GEMM (mfma_scale_f32_16x16x128_f8f6f4, unit scales) with
// FULLY fused epilogue: exp + row-sum -> device-scope atomicAdd into S
// (RMW at the coherent point — cross-XCD safe, no fence needed; R6's
// __threadfence caused per-block L2 writeback scans, +60 µs), then per-iT
// done-counter; the 32nd block of each row-tile reads its 128 S values via
// relaxed AGENT atomic loads and atomicAdds the tile's loss contribution
// into out[0]. Ordering: s_waitcnt vmcnt(0) (+ __syncthreads) guarantees
// the S-adds have completed at the coherent point before the ctr bump.
// Block = 128x128, 4 waves 2x2; each wave 64x64 via 4x4 MFMA grid, K=128
// per MFMA = whole k-tile, 8 k-iters. LDS 2x16 KB, 16B-chunk XOR swizzle
// (slot = g ^ (row&7)) keeps staging and ds_read_b128 at the bank floor.
__global__ __launch_bounds__(256) void k_gemm_sumexp(
    const unsigned char* __restrict__ z1f, const unsigned char* __restrict__ z2f,
    float* __restrict__ S, const float* __restrict__ diag,
    unsigned int* __restrict__ ctr, float* __restrict__ out) {
    __shared__ __attribute__((aligned(16))) unsigned char As[128 * BK];  // 16 KB
    __shared__ __attribute__((aligned(16))) unsigned char Bs[128 * BK];  // 16 KB
    __shared__ int sh_last;
    __shared__ float rr[4];

    const int iT = blockIdx.y, jT = blockIdx.x;
    const int lane = threadIdx.x & 63, wave = threadIdx.x >> 6;
    const int wm = wave >> 1, wn = wave & 1;     // 2x2 wave grid
    const int ml = lane & 15, q = lane >> 4;     // MFMA lane decomposition
    const int i0 = iT * 128, j0 = jT * 128;

    // staging: one wave-issue = 1 KB = 8 rows x 128 B. lane l: row = l>>3,
    // LDS chunk slot = l&7, global chunk g = (l&7) ^ (row&7).
    const int srow = lane >> 3;                       // 0..7 within issue
    const int sg = ((lane & 7) ^ (srow & 7)) * 16;    // swizzled global byte off

    // fragment-read slots for this lane (32 k-bytes [q*32, +32) of row ml)
    const int rs = ml & 7;
    const int slotL = ((2 * q) ^ rs) * 16;
    const int slotH = ((2 * q + 1) ^ rs) * 16;

    floatx4 acc[4][4];
    #pragma unroll
    for (int mt = 0; mt < 4; ++mt)
        #pragma unroll
        for (int nt = 0; nt < 4; ++nt)
            acc[mt][nt] = (floatx4){0.f, 0.f, 0.f, 0.f};

    for (int k0 = 0; k0 < DIM; k0 += BK) {
        #pragma unroll
        for (int c = 0; c < 4; ++c) {
            const int issue = wave * 4 + c;          // 0..15
            const int row = issue * 8 + srow;        // 0..127
            const unsigned char* gA = z1f + (size_t)(i0 + row) * DIM + k0 + sg;
            const unsigned char* gB = z2f + (size_t)(j0 + row) * DIM + k0 + sg;
            __builtin_amdgcn_global_load_lds(
                (const __attribute__((address_space(1))) void*)gA,
                (__attribute__((address_space(3))) void*)(As + issue * 1024), 16, 0, 0);
            __builtin_amdgcn_global_load_lds(
                (const __attribute__((address_space(1))) void*)gB,
                (__attribute__((address_space(3))) void*)(Bs + issue * 1024), 16, 0, 0);
        }
        __syncthreads();

        int8x af[4], bf[4];
        #pragma unroll
        for (int t = 0; t < 4; ++t) {
            const unsigned char* rowA = As + (wm * 64 + t * 16 + ml) * BK;
            const unsigned char* rowB = Bs + (wn * 64 + t * 16 + ml) * BK;
            int4x aL = *reinterpret_cast<const int4x*>(rowA + slotL);
            int4x aH = *reinterpret_cast<const int4x*>(rowA + slotH);
            int4x bLo = *reinterpret_cast<const int4x*>(rowB + slotL);
            int4x bHi = *reinterpret_cast<const int4x*>(rowB + slotH);
            af[t] = __builtin_shufflevector(aL, aH, 0, 1, 2, 3, 4, 5, 6, 7);
            bf[t] = __builtin_shufflevector(bLo, bHi, 0, 1, 2, 3, 4, 5, 6, 7);
        }
        #pragma unroll
        for (int mt = 0; mt < 4; ++mt)
            #pragma unroll
            for (int nt = 0; nt < 4; ++nt)
                acc[mt][nt] = __builtin_amdgcn_mfma_scale_f32_16x16x128_f8f6f4(
                    af[mt], bf[nt], acc[mt][nt],
                    0 /*fmt A = fp8*/, 0 /*fmt B = fp8*/,
                    0, 0x7F /*scale A = 1.0*/, 0, 0x7F /*scale B = 1.0*/);
        __syncthreads();
    }

    // Epilogue. C/D layout: col=lane&15, row=q*4+reg. exp + row-sum over the
    // wave's 64 columns, butterfly across 16 ml-lanes; combine the two
    // wn-waves via LDS; one device-scope atomicAdd per (block, row) into S.
    float vv[4][4];
    #pragma unroll
    for (int mt = 0; mt < 4; ++mt) {
        #pragma unroll
        for (int r = 0; r < 4; ++r) {
            float v = 0.f;
            #pragma unroll
            for (int nt = 0; nt < 4; ++nt)
                v += __builtin_amdgcn_exp2f(acc[mt][nt][r] * EXP_SCALE);
            v += __shfl_xor(v, 1, 64);
            v += __shfl_xor(v, 2, 64);
            v += __shfl_xor(v, 4, 64);
            v += __shfl_xor(v, 8, 64);
            vv[mt][r] = v;
        }
    }
    float* Pl = reinterpret_cast<float*>(As);  // reuse (all LDS reads done)
    if (wn == 1 && ml == 0) {
        #pragma unroll
        for (int mt = 0; mt < 4; ++mt)
            #pragma unroll
            for (int r = 0; r < 4; ++r)
                Pl[wm * 64 + mt * 16 + q * 4 + r] = vv[mt][r];
    }
    __syncthreads();
    if (wn == 0 && ml == 0) {
        #pragma unroll
        for (int mt = 0; mt < 4; ++mt)
            #pragma unroll
            for (int r = 0; r < 4; ++r) {
                const int ri = wm * 64 + mt * 16 + q * 4 + r;
                atomicAdd(&S[i0 + ri], vv[mt][r] + Pl[ri]);
            }
    }

    // Drain the S atomics (ack at coherent point), then bump the per-iT
    // counter. No __threadfence — atomic RMWs are already coherent.
    __builtin_amdgcn_s_waitcnt(0);
    __syncthreads();
    if (threadIdx.x == 0) {
        unsigned int old = atomicAdd(&ctr[iT], 1u);
        sh_last = (old == NJT - 1);
    }
    __syncthreads();
    if (sh_last) {
        const int t = threadIdx.x;
        float v = 0.f;
        if (t < 128) {
            float s = __hip_atomic_load(&S[i0 + t], __ATOMIC_RELAXED,
                                        __HIP_MEMORY_SCOPE_AGENT);
            v = logf(s) - diag[i0 + t];
        }
        #pragma unroll
        for (int m = 32; m >= 1; m >>= 1)
            v += __shfl_xor(v, m, 64);
        if ((t & 63) == 0) rr[t >> 6] = v;
        __syncthreads();
        if (t == 0)
            atomicAdd(out, (rr[0] + rr[1] + rr[2] + rr[3]) * (1.0f / N_ROWS));
    }
}

extern "C" void kernel_launch(void* const* d_in, const int* in_sizes, int n_in,
                              void* d_out, int out_size, void* d_ws, size_t ws_size,
                              hipStream_t stream) {
    const float* z1 = (const float*)d_in[0];
    const float* z2 = (const float*)d_in[1];

    char* ws = (char*)d_ws;
    unsigned char* z1f = (unsigned char*)ws;                                     // 4 MB
    unsigned char* z2f = (unsigned char*)(ws + (size_t)N_ROWS * DIM);            // 4 MB
    float* diag = (float*)(ws + (size_t)N_ROWS * DIM * 2);                       // 16 KB
    float* S = diag + N_ROWS;                                                    // 16 KB
    unsigned int* ctr = (unsigned int*)(S + N_ROWS);                             // 128 B

    k_normalize<<<N_ROWS / 4, 256, 0, stream>>>(z1, z2, z1f, z2f, diag, S, ctr,
                                                (float*)d_out);
    k_gemm_sumexp<<<dim3(NJT, 32), 256, 0, stream>>>(z1f, z2f, S, diag, ctr,
                                                     (float*)d_out);
}

// Round 11
// 101.319 us; speedup vs baseline: 1.0880x; 1.0880x over previous
//
#include <hip/hip_runtime.h>

#define N_ROWS 4096
#define DIM 1024
#define INV_T (1.0f / 0.07f)
#define FP8_SCALE 16.0f
// acc = (16*c1)·(16*c2) = 256*cos; exp2 argument = acc * INV_T * log2(e) / 256
#define EXP_SCALE (INV_T * 1.44269504088896f / 256.0f)
#define BK 128   // fp8 elements per k-tile (= 128 B rows in LDS) = one MFMA-K
#define NJT 32   // number of j-tiles (= grid.x of gemm)

typedef __attribute__((ext_vector_type(4))) float floatx4;
typedef __attribute__((ext_vector_type(4))) int int4x;
typedef __attribute__((ext_vector_type(8))) int int8x;

// fp32 -> OCP e4m3fn. Prefer the HW packed convert (v_cvt_pk_fp8_f32, RNE,
// 2 values/inst); software RNE fallback if the builtin is unavailable.
#if __has_builtin(__builtin_amdgcn_cvt_pk_fp8_f32)
__device__ inline unsigned int pack4_e4m3(float x, float y, float z, float w) {
    int p = __builtin_amdgcn_cvt_pk_fp8_f32(x, y, 0, false);   // low word
    p = __builtin_amdgcn_cvt_pk_fp8_f32(z, w, p, true);        // high word
    return (unsigned int)p;
}
#else
__device__ inline unsigned int f2e4m3(float x) {
    unsigned int u = __float_as_uint(x);
    unsigned int s = (u >> 24) & 0x80u;
    int e = (int)((u >> 23) & 0xffu);
    unsigned int m = u & 0x7fffffu;
    if (e < 121) return s;              // FTZ (|x| < 2^-6)
    unsigned int t = m >> 20;
    unsigned int rest = m & 0xFFFFFu;
    t += (rest > 0x80000u) || (rest == 0x80000u && (t & 1u));  // RNE
    int e8 = e - 120;
    if (t == 8u) { t = 0u; e8 += 1; }
    return s | ((unsigned int)e8 << 3) | t;
}
__device__ inline unsigned int pack4_e4m3(float x, float y, float z, float w) {
    return f2e4m3(x) | (f2e4m3(y) << 8) | (f2e4m3(z) << 16) | (f2e4m3(w) << 24);
}
#endif

// One WAVE per row (4 rows / 256-thread block). Emits fp8 normalized rows
// (scaled by 16) + exact fp32 diagonal logit. Block 0 zeroes out[0].
__global__ __launch_bounds__(256) void k_normalize(
    const float* __restrict__ z1, const float* __restrict__ z2,
    unsigned char* __restrict__ z1f, unsigned char* __restrict__ z2f,
    float* __restrict__ diag, float* __restrict__ out) {
    const int lane = threadIdx.x & 63, wave = threadIdx.x >> 6;
    const int row = blockIdx.x * 4 + wave;

    if (blockIdx.x == 0 && threadIdx.x == 0) out[0] = 0.f;

    const float4* A = reinterpret_cast<const float4*>(z1 + (size_t)row * DIM);
    const float4* B = reinterpret_cast<const float4*>(z2 + (size_t)row * DIM);
    float4 a[4], b[4];
    #pragma unroll
    for (int rep = 0; rep < 4; ++rep) {
        a[rep] = A[lane + 64 * rep];
        b[rep] = B[lane + 64 * rep];
    }

    float s11 = 0.f, s22 = 0.f, s12 = 0.f;
    #pragma unroll
    for (int rep = 0; rep < 4; ++rep) {
        s11 += a[rep].x * a[rep].x + a[rep].y * a[rep].y
             + a[rep].z * a[rep].z + a[rep].w * a[rep].w;
        s22 += b[rep].x * b[rep].x + b[rep].y * b[rep].y
             + b[rep].z * b[rep].z + b[rep].w * b[rep].w;
        s12 += a[rep].x * b[rep].x + a[rep].y * b[rep].y
             + a[rep].z * b[rep].z + a[rep].w * b[rep].w;
    }
    #pragma unroll
    for (int m = 32; m >= 1; m >>= 1) {
        s11 += __shfl_xor(s11, m, 64);
        s22 += __shfl_xor(s22, m, 64);
        s12 += __shfl_xor(s12, m, 64);
    }

    const float n1 = fmaxf(sqrtf(s11), 1e-12f);
    const float n2 = fmaxf(sqrtf(s22), 1e-12f);
    if (lane == 0) diag[row] = s12 / (n1 * n2) * INV_T;
    const float i1 = FP8_SCALE / n1, i2 = FP8_SCALE / n2;

    unsigned int* O1 = reinterpret_cast<unsigned int*>(z1f + (size_t)row * DIM);
    unsigned int* O2 = reinterpret_cast<unsigned int*>(z2f + (size_t)row * DIM);
    #pragma unroll
    for (int rep = 0; rep < 4; ++rep) {
        O1[lane + 64 * rep] = pack4_e4m3(a[rep].x * i1, a[rep].y * i1,
                                         a[rep].z * i1, a[rep].w * i1);
        O2[lane + 64 * rep] = pack4_e4m3(b[rep].x * i2, b[rep].y * i2,
                                         b[rep].z * i2, b[rep].w * i2);
    }
}

// MX-scaled fp8 GEMM: mfma_scale_f32_16x16x128_f8f6f4 with unit scales
// (E8M0 0x7F = 1.0) — 2x the non-scaled fp8 MFMA rate, K=128 per
// instruction = whole BK tile, so one kk-step and 16 MFMAs per k-iter.
// Block = 128x128, 4 waves 2x2; each wave 64x64 via 4x4 MFMA grid.
// LDS 2x16 KB. 16B-chunk XOR swizzle (slot = g ^ (row&7)) keeps both the
// staging (global side permuted, LDS side forced base+lane*16) and the
// ds_read_b128 fragment reads at the wave64 bank floor. Fused exp+row-sum
// epilogue, per-jT partial output (no atomics, no fences — R6/R10 showed
// any in-GEMM cross-block reduction machinery costs more than a dispatch).
__global__ __launch_bounds__(256) void k_gemm_sumexp(
    const unsigned char* __restrict__ z1f, const unsigned char* __restrict__ z2f,
    float* __restrict__ P) {
    __shared__ __attribute__((aligned(16))) unsigned char As[128 * BK];  // 16 KB
    __shared__ __attribute__((aligned(16))) unsigned char Bs[128 * BK];  // 16 KB

    const int iT = blockIdx.y, jT = blockIdx.x;
    const int lane = threadIdx.x & 63, wave = threadIdx.x >> 6;
    const int wm = wave >> 1, wn = wave & 1;     // 2x2 wave grid
    const int ml = lane & 15, q = lane >> 4;     // MFMA lane decomposition
    const int i0 = iT * 128, j0 = jT * 128;

    // staging: one wave-issue = 1 KB = 8 rows x 128 B. lane l: row = l>>3,
    // LDS chunk slot = l&7, global chunk g = (l&7) ^ (row&7).
    const int srow = lane >> 3;                       // 0..7 within issue
    const int sg = ((lane & 7) ^ (srow & 7)) * 16;    // swizzled global byte off

    // fragment-read slots for this lane (32 k-bytes [q*32, +32) of row ml)
    const int rs = ml & 7;
    const int slotL = ((2 * q) ^ rs) * 16;
    const int slotH = ((2 * q + 1) ^ rs) * 16;

    floatx4 acc[4][4];
    #pragma unroll
    for (int mt = 0; mt < 4; ++mt)
        #pragma unroll
        for (int nt = 0; nt < 4; ++nt)
            acc[mt][nt] = (floatx4){0.f, 0.f, 0.f, 0.f};

    for (int k0 = 0; k0 < DIM; k0 += BK) {
        #pragma unroll
        for (int c = 0; c < 4; ++c) {
            const int issue = wave * 4 + c;          // 0..15
            const int row = issue * 8 + srow;        // 0..127
            const unsigned char* gA = z1f + (size_t)(i0 + row) * DIM + k0 + sg;
            const unsigned char* gB = z2f + (size_t)(j0 + row) * DIM + k0 + sg;
            __builtin_amdgcn_global_load_lds(
                (const __attribute__((address_space(1))) void*)gA,
                (__attribute__((address_space(3))) void*)(As + issue * 1024), 16, 0, 0);
            __builtin_amdgcn_global_load_lds(
                (const __attribute__((address_space(1))) void*)gB,
                (__attribute__((address_space(3))) void*)(Bs + issue * 1024), 16, 0, 0);
        }
        __syncthreads();

        int8x af[4], bf[4];
        #pragma unroll
        for (int t = 0; t < 4; ++t) {
            const unsigned char* rowA = As + (wm * 64 + t * 16 + ml) * BK;
            const unsigned char* rowB = Bs + (wn * 64 + t * 16 + ml) * BK;
            int4x aL = *reinterpret_cast<const int4x*>(rowA + slotL);
            int4x aH = *reinterpret_cast<const int4x*>(rowA + slotH);
            int4x bLo = *reinterpret_cast<const int4x*>(rowB + slotL);
            int4x bHi = *reinterpret_cast<const int4x*>(rowB + slotH);
            af[t] = __builtin_shufflevector(aL, aH, 0, 1, 2, 3, 4, 5, 6, 7);
            bf[t] = __builtin_shufflevector(bLo, bHi, 0, 1, 2, 3, 4, 5, 6, 7);
        }
        #pragma unroll
        for (int mt = 0; mt < 4; ++mt)
            #pragma unroll
            for (int nt = 0; nt < 4; ++nt)
                acc[mt][nt] = __builtin_amdgcn_mfma_scale_f32_16x16x128_f8f6f4(
                    af[mt], bf[nt], acc[mt][nt],
                    0 /*fmt A = fp8*/, 0 /*fmt B = fp8*/,
                    0, 0x7F /*scale A = 1.0*/, 0, 0x7F /*scale B = 1.0*/);
        __syncthreads();
    }

    // Epilogue. C/D layout: col=lane&15, row=q*4+reg. exp + row-sum over the
    // wave's 64 columns, butterfly across 16 ml-lanes; combine the two
    // wn-waves via LDS; one plain store per (jT, i).
    float vv[4][4];
    #pragma unroll
    for (int mt = 0; mt < 4; ++mt) {
        #pragma unroll
        for (int r = 0; r < 4; ++r) {
            float v = 0.f;
            #pragma unroll
            for (int nt = 0; nt < 4; ++nt)
                v += __builtin_amdgcn_exp2f(acc[mt][nt][r] * EXP_SCALE);
            v += __shfl_xor(v, 1, 64);
            v += __shfl_xor(v, 2, 64);
            v += __shfl_xor(v, 4, 64);
            v += __shfl_xor(v, 8, 64);
            vv[mt][r] = v;
        }
    }
    float* Pl = reinterpret_cast<float*>(As);  // reuse (all LDS reads done)
    if (wn == 1 && ml == 0) {
        #pragma unroll
        for (int mt = 0; mt < 4; ++mt)
            #pragma unroll
            for (int r = 0; r < 4; ++r)
                Pl[wm * 64 + mt * 16 + q * 4 + r] = vv[mt][r];
    }
    __syncthreads();
    if (wn == 0 && ml == 0) {
        #pragma unroll
        for (int mt = 0; mt < 4; ++mt)
            #pragma unroll
            for (int r = 0; r < 4; ++r) {
                const int ri = wm * 64 + mt * 16 + q * 4 + r;
                P[jT * N_ROWS + i0 + ri] = vv[mt][r] + Pl[ri];
            }
    }
}

// 32 blocks x 128 threads: one row per thread, coalesced P reads,
// block partial-sum -> atomicAdd into out[0] (zeroed by k_normalize).
__global__ __launch_bounds__(128) void k_finalize(
    const float* __restrict__ P, const float* __restrict__ diag,
    float* __restrict__ out) {
    const int t = threadIdx.x;
    const int i = blockIdx.x * 128 + t;
    float s = 0.f;
    #pragma unroll
    for (int jt = 0; jt < NJT; ++jt)
        s += P[jt * N_ROWS + i];
    float v = logf(s) - diag[i];
    #pragma unroll
    for (int m = 32; m >= 1; m >>= 1)
        v += __shfl_xor(v, m, 64);
    __shared__ float r[2];
    if ((t & 63) == 0) r[t >> 6] = v;
    __syncthreads();
    if (t == 0) atomicAdd(out, (r[0] + r[1]) * (1.0f / N_ROWS));
}

extern "C" void kernel_launch(void* const* d_in, const int* in_sizes, int n_in,
                              void* d_out, int out_size, void* d_ws, size_t ws_size,
                              hipStream_t stream) {
    const float* z1 = (const float*)d_in[0];
    const float* z2 = (const float*)d_in[1];

    char* ws = (char*)d_ws;
    unsigned char* z1f = (unsigned char*)ws;                                     // 4 MB
    unsigned char* z2f = (unsigned char*)(ws + (size_t)N_ROWS * DIM);            // 4 MB
    float* diag = (float*)(ws + (size_t)N_ROWS * DIM * 2);                       // 16 KB
    float* P = diag + N_ROWS;                                                    // 512 KB

    k_normalize<<<N_ROWS / 4, 256, 0, stream>>>(z1, z2, z1f, z2f, diag,
                                                (float*)d_out);
    k_gemm_sumexp<<<dim3(NJT, 32), 256, 0, stream>>>(z1f, z2f, P);
    k_finalize<<<32, 128, 0, stream>>>(P, diag, (float*)d_out);
}